// Round 9
// baseline (442.347 us; speedup 1.0000x reference)
//
#include <hip/hip_runtime.h>

// GNN NodeEncoder: 2 layers of
//   h = relu(x@Wr + br + mean_in(x[src])@W1 + mean_out(x[dst])@W2)
// Algebra: scatter_mean((x@W)[src],dst) == scatter_mean(x[src],dst)@W -> aggregate
// RAW features, apply weights after as an MFMA GEMM (split-bf16 hi/lo).
// CSR build is BINNED (512-node buckets): r3 profile showed scattered 4B writes
// cost 163MB HBM for 10MB payload; binned fill writes each bucket's ci region
// from ONE block. r7 profile: gathers dominate (91us each, FETCH 279MB, VALU 35%)
// -> this rev doubles per-wave MLP (dual-dir 4-deep predicated unroll, 32 rows
// in flight) to test latency-bound vs L3-BW-bound.

typedef __bf16 bf16x8 __attribute__((ext_vector_type(8)));
typedef float  f32x4  __attribute__((ext_vector_type(4)));

#define BSHIFT 9          // 512 nodes per bucket
#define NBMAX  256        // max buckets (N <= 131072, and id must fit 17 bits)
#define CAPLOG 13         // 8192 entries per bucket (mean 6378, sigma ~80 -> +22 sigma)
#define CAP    (1 << CAPLOG)

// ---------------- binned CSR build ----------------
// Pass A: per-block LDS histogram over an 8192-edge chunk, reserve global space
// with one atomic per (block,bucket,dir), then append packed entries:
//   entry = (local_node_id << 17) | neighbor      (N < 2^17, local id < 512)
__launch_bounds__(256)
__global__ void k_bin(const int* __restrict__ ei, int E,
                      int* __restrict__ gcnt /* [2*NBMAX] */,
                      unsigned* __restrict__ binbuf /* [2*NBMAX*CAP] */) {
    __shared__ int lcnt[2 * NBMAX];
    const int tid = threadIdx.x;
    lcnt[tid] = 0; lcnt[NBMAX + tid] = 0;
    __syncthreads();
    const int start = blockIdx.x * 8192;
    const int end = min(start + 8192, E);
    for (int e = start + tid; e < end; e += 256) {
        int s = ei[e], d = ei[E + e];
        atomicAdd(&lcnt[d >> BSHIFT], 1);           // in-dir: bucket by dst
        atomicAdd(&lcnt[NBMAX + (s >> BSHIFT)], 1); // out-dir: bucket by src
    }
    __syncthreads();
    {   // reserve contiguous runs in each bucket; cursor = global base
        int c0 = lcnt[tid], c1 = lcnt[NBMAX + tid];
        int b0 = c0 ? atomicAdd(&gcnt[tid], c0) : 0;
        int b1 = c1 ? atomicAdd(&gcnt[NBMAX + tid], c1) : 0;
        lcnt[tid] = b0; lcnt[NBMAX + tid] = b1;
    }
    __syncthreads();
    for (int e = start + tid; e < end; e += 256) {  // ei re-read is L2-hot
        int s = ei[e], d = ei[E + e];
        int bi = d >> BSHIFT;
        int p = atomicAdd(&lcnt[bi], 1);
        if (p < CAP)
            binbuf[(bi << CAPLOG) + p] = ((unsigned)(d & 511) << 17) | (unsigned)s;
        int bo = s >> BSHIFT;
        int p2 = atomicAdd(&lcnt[NBMAX + bo], 1);
        if (p2 < CAP)
            binbuf[((NBMAX + bo) << CAPLOG) + p2] = ((unsigned)(s & 511) << 17) | (unsigned)d;
    }
}

// Pass B: per (bucket,dir) block. In-LDS scan of gcnt gives the bucket base
// (replaces the k_scanbase launch); LDS degree histogram -> Blelloch exclusive
// scan -> write rp (contiguous) + scatter ci via LDS cursors. Each bucket's ci
// region (~25KB) is written by ONE block.
__launch_bounds__(256)
__global__ void k_binfill2(const unsigned* __restrict__ binbuf, const int* __restrict__ gcnt,
                           int n,
                           int* __restrict__ rp_in, int* __restrict__ rp_out,
                           int* __restrict__ ci_in, int* __restrict__ ci_out) {
    __shared__ int h[512];     // histogram -> exclusive scan
    __shared__ int cur[512];   // scatter cursors
    __shared__ int gb[NBMAX];  // bucket-total scan for base offset
    __shared__ int s_tot;
    const int dir = blockIdx.y, bkt = blockIdx.x, tid = threadIdx.x;
    int* rp = dir ? rp_out : rp_in;
    int* ci = dir ? ci_out : ci_in;
    h[tid] = 0; h[256 + tid] = 0;
    gb[tid] = gcnt[dir * NBMAX + tid];
    __syncthreads();
    // inclusive scan of bucket totals (Hillis-Steele over 256)
    for (int off = 1; off < NBMAX; off <<= 1) {
        int t = (tid >= off) ? gb[tid - off] : 0;
        __syncthreads();
        gb[tid] += t;
        __syncthreads();
    }
    const int base_off = bkt ? gb[bkt - 1] : 0;
    const int cnt = min(gcnt[dir * NBMAX + bkt], CAP);
    const unsigned* buf = binbuf + (((size_t)dir * NBMAX + bkt) << CAPLOG);
    for (int i = tid; i < cnt; i += 256)
        atomicAdd(&h[buf[i] >> 17], 1);
    __syncthreads();
    // Blelloch up-sweep
    for (int d = 1; d < 512; d <<= 1) {
        int idx = (tid + 1) * (d << 1) - 1;
        if (idx < 512) h[idx] += h[idx - d];
        __syncthreads();
    }
    if (tid == 0) { s_tot = h[511]; h[511] = 0; }
    __syncthreads();
    // down-sweep -> exclusive scan
    for (int d = 256; d >= 1; d >>= 1) {
        int idx = (tid + 1) * (d << 1) - 1;
        if (idx < 512) { int t = h[idx - d]; h[idx - d] = h[idx]; h[idx] += t; }
        __syncthreads();
    }
    const int nodebase = bkt << BSHIFT;
    for (int i = tid; i < 512; i += 256) {
        int nd = nodebase + i;
        int v = base_off + h[i];
        cur[i] = v;
        if (nd < n) rp[nd] = v;
    }
    if (tid == 0 && ((n - 1) >> BSHIFT) == bkt)
        rp[n] = base_off + s_tot;           // final row pointer
    __syncthreads();
    for (int i = tid; i < cnt; i += 256) {  // buf re-read is L2-hot (~25KB)
        unsigned ent = buf[i];
        int slot = atomicAdd(&cur[ent >> 17], 1);
        ci[slot] = (int)(ent & 0x1FFFFu);
    }
}

// ---------------- weight prep (both layers in one launch) ----------------
// WcT: [64 n][128 k] (k<64 from W1, k>=64 from W2); WrT: [64 n][64 k]; split bf16.
__global__ void k_prep2(const float* __restrict__ W1a, const float* __restrict__ W2a,
                        const float* __restrict__ Wra,
                        __bf16* __restrict__ WcTha, __bf16* __restrict__ WcTla,
                        __bf16* __restrict__ WrTha, __bf16* __restrict__ WrTla,
                        const float* __restrict__ W1b, const float* __restrict__ W2b,
                        const float* __restrict__ Wrb,
                        __bf16* __restrict__ WcThb, __bf16* __restrict__ WcTlb,
                        __bf16* __restrict__ WrThb, __bf16* __restrict__ WrTlb) {
    const float *W1, *W2, *Wr;
    __bf16 *Wch, *Wcl, *Wrh, *Wrl;
    if (blockIdx.y == 0) { W1 = W1a; W2 = W2a; Wr = Wra; Wch = WcTha; Wcl = WcTla; Wrh = WrTha; Wrl = WrTla; }
    else                 { W1 = W1b; W2 = W2b; Wr = Wrb; Wch = WcThb; Wcl = WcTlb; Wrh = WrThb; Wrl = WrTlb; }
    int i = blockIdx.x * 256 + threadIdx.x;  // 12288 total
    if (i < 8192) {
        int nn = i >> 7, k = i & 127;
        float w = (k < 64) ? W1[k * 64 + nn] : W2[(k - 64) * 64 + nn];
        __bf16 h = (__bf16)w;
        Wch[i] = h;
        Wcl[i] = (__bf16)(w - (float)h);
    } else if (i < 12288) {
        int j = i - 8192;
        int nn = j >> 6, k = j & 63;
        float w = Wr[k * 64 + nn];
        __bf16 h = (__bf16)w;
        Wrh[j] = h;
        Wrl[j] = (__bf16)(w - (float)h);
    }
}

// ---------------- gather: dual-dir 4-deep predicated unroll ----------------
// lane = 16*sub + q. Both directions processed in ONE loop: up to 32 rows in
// flight per wave (2 dirs x 4 unroll x 4 sub-rows) vs 8 before -- targets the
// latency-bound hypothesis (r7: VALUBusy 35%, occ 75%, FETCH 46%).
__launch_bounds__(256, 6)
__global__ void k_gather(const float* __restrict__ Hin,
                         const int* __restrict__ rp_in, const int* __restrict__ ci_in,
                         const int* __restrict__ rp_out, const int* __restrict__ ci_out,
                         __bf16* __restrict__ Ah, __bf16* __restrict__ Al, int n) {
    const int lane = threadIdx.x & 63;
    const int wid  = threadIdx.x >> 6;
    const int v = blockIdx.x * 4 + wid;
    if (v >= n) return;
    const int q = lane & 15, sub = lane >> 4;

    const int s0 = rp_in[v],  e0 = rp_in[v + 1],  len0 = e0 - s0;
    const int s1 = rp_out[v], e1 = rp_out[v + 1], len1 = e1 - s1;
    const int mlen = max(len0, len1);
    const float* __restrict__ hq = Hin + q * 4;

    float4 a0 = {0.f, 0.f, 0.f, 0.f}, a1 = {0.f, 0.f, 0.f, 0.f};
    for (int t = sub; t < mlen; t += 16) {
        #pragma unroll
        for (int u = 0; u < 4; ++u) {
            int r = t + u * 4;   // uniform within a 16-lane sub-group
            if (r < len0) {
                int nd = ci_in[s0 + r];
                float4 f = *(const float4*)(hq + (size_t)nd * 64);
                a0.x += f.x; a0.y += f.y; a0.z += f.z; a0.w += f.w;
            }
            if (r < len1) {
                int nd = ci_out[s1 + r];
                float4 f = *(const float4*)(hq + (size_t)nd * 64);
                a1.x += f.x; a1.y += f.y; a1.z += f.z; a1.w += f.w;
            }
        }
    }
    // reduce across the 4 sub groups (lanes ^16, ^32)
    #pragma unroll
    for (int m = 16; m <= 32; m <<= 1) {
        a0.x += __shfl_xor(a0.x, m, 64); a0.y += __shfl_xor(a0.y, m, 64);
        a0.z += __shfl_xor(a0.z, m, 64); a0.w += __shfl_xor(a0.w, m, 64);
        a1.x += __shfl_xor(a1.x, m, 64); a1.y += __shfl_xor(a1.y, m, 64);
        a1.z += __shfl_xor(a1.z, m, 64); a1.w += __shfl_xor(a1.w, m, 64);
    }
    float inv0 = 1.0f / (float)max(len0, 1);
    float inv1 = 1.0f / (float)max(len1, 1);
    a0.x *= inv0; a0.y *= inv0; a0.z *= inv0; a0.w *= inv0;
    a1.x *= inv1; a1.y *= inv1; a1.z *= inv1; a1.w *= inv1;

    if (sub == 0) {  // 16 lanes write each 64-col block as split bf16
        #pragma unroll
        for (int dir = 0; dir < 2; ++dir) {
            float m[4] = {dir ? a1.x : a0.x, dir ? a1.y : a0.y,
                          dir ? a1.z : a0.z, dir ? a1.w : a0.w};
            union { __bf16 h[4]; uint2 u2; } ph, pl;
            #pragma unroll
            for (int c = 0; c < 4; ++c) {
                __bf16 h = (__bf16)m[c];
                ph.h[c] = h;
                pl.h[c] = (__bf16)(m[c] - (float)h);
            }
            size_t off = (size_t)v * 128 + dir * 64 + q * 4;
            *(uint2*)(Ah + off) = ph.u2;
            *(uint2*)(Al + off) = pl.u2;
        }
    }
}

// ---------------- MFMA GEMM: out = relu(A@Wcat + Hin@Wr + br) ----------------
// mfma_f32_16x16x32_bf16; identical k-packing for A and B makes the internal
// k-order cancel. C/D: col = lane&15, row = (lane>>4)*4 + reg  [verified m89]
__global__ void k_gemm(const __bf16* __restrict__ Ah, const __bf16* __restrict__ Al,
                       const float* __restrict__ Hin,
                       const __bf16* __restrict__ WcT_h, const __bf16* __restrict__ WcT_l,
                       const __bf16* __restrict__ WrT_h, const __bf16* __restrict__ WrT_l,
                       const float* __restrict__ br, float* __restrict__ Hout, int n) {
    const int lane = threadIdx.x & 63;
    const int wid  = threadIdx.x >> 6;
    const int q = lane & 15, sub = lane >> 4;
    const int rowbase = blockIdx.x * 64 + wid * 16;
    const int arow = min(rowbase + q, n - 1);

    f32x4 acc[4];
    #pragma unroll
    for (int nf = 0; nf < 4; ++nf) acc[nf] = (f32x4){0.f, 0.f, 0.f, 0.f};

    // A @ Wcat  (K = 128)
    #pragma unroll
    for (int ks = 0; ks < 4; ++ks) {
        const size_t ao = (size_t)arow * 128 + ks * 32 + sub * 8;
        bf16x8 a_h = *(const bf16x8*)(Ah + ao);
        bf16x8 a_l = *(const bf16x8*)(Al + ao);
        #pragma unroll
        for (int nf = 0; nf < 4; ++nf) {
            const size_t bo = (size_t)(nf * 16 + q) * 128 + ks * 32 + sub * 8;
            bf16x8 b_h = *(const bf16x8*)(WcT_h + bo);
            bf16x8 b_l = *(const bf16x8*)(WcT_l + bo);
            acc[nf] = __builtin_amdgcn_mfma_f32_16x16x32_bf16(a_h, b_h, acc[nf], 0, 0, 0);
            acc[nf] = __builtin_amdgcn_mfma_f32_16x16x32_bf16(a_h, b_l, acc[nf], 0, 0, 0);
            acc[nf] = __builtin_amdgcn_mfma_f32_16x16x32_bf16(a_l, b_h, acc[nf], 0, 0, 0);
        }
    }
    // Hin @ Wr  (K = 64), fp32 -> hi/lo split in-register
    #pragma unroll
    for (int ks = 0; ks < 2; ++ks) {
        const float* hp = Hin + (size_t)arow * 64 + ks * 32 + sub * 8;
        float4 h0 = *(const float4*)hp;
        float4 h1 = *(const float4*)(hp + 4);
        float hf[8] = {h0.x, h0.y, h0.z, h0.w, h1.x, h1.y, h1.z, h1.w};
        bf16x8 a_h, a_l;
        #pragma unroll
        for (int c = 0; c < 8; ++c) {
            __bf16 h = (__bf16)hf[c];
            a_h[c] = h;
            a_l[c] = (__bf16)(hf[c] - (float)h);
        }
        #pragma unroll
        for (int nf = 0; nf < 4; ++nf) {
            const size_t bo = (size_t)(nf * 16 + q) * 64 + ks * 32 + sub * 8;
            bf16x8 b_h = *(const bf16x8*)(WrT_h + bo);
            bf16x8 b_l = *(const bf16x8*)(WrT_l + bo);
            acc[nf] = __builtin_amdgcn_mfma_f32_16x16x32_bf16(a_h, b_h, acc[nf], 0, 0, 0);
            acc[nf] = __builtin_amdgcn_mfma_f32_16x16x32_bf16(a_h, b_l, acc[nf], 0, 0, 0);
            acc[nf] = __builtin_amdgcn_mfma_f32_16x16x32_bf16(a_l, b_h, acc[nf], 0, 0, 0);
        }
    }
    #pragma unroll
    for (int nf = 0; nf < 4; ++nf) {
        int col = nf * 16 + q;
        float b = br[col];
        #pragma unroll
        for (int reg = 0; reg < 4; ++reg) {
            int row = rowbase + sub * 4 + reg;
            if (row < n)
                Hout[(size_t)row * 64 + col] = fmaxf(acc[nf][reg] + b, 0.f);
        }
    }
}

extern "C" void kernel_launch(void* const* d_in, const int* in_sizes, int n_in,
                              void* d_out, int out_size, void* d_ws, size_t ws_size,
                              hipStream_t stream) {
    const float* x    = (const float*)d_in[0];
    const int*   ei   = (const int*)d_in[1];
    const float* W1_0 = (const float*)d_in[2];
    const float* W2_0 = (const float*)d_in[3];
    const float* Wr_0 = (const float*)d_in[4];
    const float* br_0 = (const float*)d_in[5];
    const float* W1_1 = (const float*)d_in[6];
    const float* W2_1 = (const float*)d_in[7];
    const float* Wr_1 = (const float*)d_in[8];
    const float* br_1 = (const float*)d_in[9];
    float* out = (float*)d_out;

    const int N = in_sizes[0] / 64;
    const int E = in_sizes[1] / 2;
    const int NB = (N + 511) >> BSHIFT;       // 196 buckets (<= NBMAX)

    // bump allocator over d_ws (re-poisoned every call -> rebuild everything)
    char* p = (char*)d_ws;
    auto alloc = [&](size_t bytes) { char* r = p; p += (bytes + 255) & ~255ULL; return r; };

    int* rp_in   = (int*)alloc(((size_t)N + 1) * 4);
    int* rp_out  = (int*)alloc(((size_t)N + 1) * 4);
    int* gcnt    = (int*)alloc(2 * NBMAX * 4);
    int* ci_in   = (int*)alloc((size_t)E * 4);
    int* ci_out  = (int*)alloc((size_t)E * 4);
    __bf16* Ah   = (__bf16*)alloc((size_t)N * 128 * 2);
    __bf16* Al   = (__bf16*)alloc((size_t)N * 128 * 2);
    float* H     = (float*)alloc((size_t)N * 64 * 4);
    __bf16* WcT_h0 = (__bf16*)alloc(8192 * 2);
    __bf16* WcT_l0 = (__bf16*)alloc(8192 * 2);
    __bf16* WrT_h0 = (__bf16*)alloc(4096 * 2);
    __bf16* WrT_l0 = (__bf16*)alloc(4096 * 2);
    __bf16* WcT_h1 = (__bf16*)alloc(8192 * 2);
    __bf16* WcT_l1 = (__bf16*)alloc(8192 * 2);
    __bf16* WrT_h1 = (__bf16*)alloc(4096 * 2);
    __bf16* WrT_l1 = (__bf16*)alloc(4096 * 2);

    // binbuf (2*NBMAX*CAP*4B = 16.8MB) aliases Ah/Al: dead before first k_gather.
    unsigned* binbuf = (unsigned*)Ah;

    hipMemsetAsync(gcnt, 0, 2 * NBMAX * 4, stream);

    int bb = (E + 8191) / 8192;
    k_bin<<<bb, 256, 0, stream>>>(ei, E, gcnt, binbuf);
    k_binfill2<<<dim3(NB, 2), 256, 0, stream>>>(binbuf, gcnt, N,
                                                rp_in, rp_out, ci_in, ci_out);
    k_prep2<<<dim3(48, 2), 256, 0, stream>>>(W1_0, W2_0, Wr_0, WcT_h0, WcT_l0, WrT_h0, WrT_l0,
                                             W1_1, W2_1, Wr_1, WcT_h1, WcT_l1, WrT_h1, WrT_l1);

    int gb = (N + 3) / 4;           // 4 nodes per 256-thread block
    int mb = (N + 63) / 64;         // 64 rows per GEMM block

    k_gather<<<gb, 256, 0, stream>>>(x, rp_in, ci_in, rp_out, ci_out, Ah, Al, N);
    k_gemm<<<mb, 256, 0, stream>>>(Ah, Al, x, WcT_h0, WcT_l0, WrT_h0, WrT_l0, br_0, H, N);

    k_gather<<<gb, 256, 0, stream>>>(H, rp_in, ci_in, rp_out, ci_out, Ah, Al, N);
    k_gemm<<<mb, 256, 0, stream>>>(Ah, Al, H, WcT_h1, WcT_l1, WrT_h1, WrT_l1, br_1, out, N);
}

// Round 10
// 402.782 us; speedup vs baseline: 1.0982x; 1.0982x over previous
//
#include <hip/hip_runtime.h>

// GNN NodeEncoder: 2 layers of
//   h = relu(x@Wr + br + mean_in(x[src])@W1 + mean_out(x[dst])@W2)
// Algebra: scatter_mean((x@W)[src],dst) == scatter_mean(x[src],dst)@W -> aggregate
// RAW features, apply weights after as an MFMA GEMM (split-bf16 hi/lo).
// CSR build BINNED (512-node buckets): r3 showed scattered 4B writes cost 163MB
// HBM for 10MB payload. r7/r9 A/B: gather is fetch-throughput-bound (~3TB/s on
// random 256B rows; FETCH flat at 279MB under 4x concurrency) -> this rev halves
// gather bytes with an fp16 feature table (means still fp32-accumulated; GEMM's
// x@Wr path keeps fp32). Gather loop reverted to the faster r7 shape.

typedef __bf16 bf16x8 __attribute__((ext_vector_type(8)));
typedef float  f32x4  __attribute__((ext_vector_type(4)));
typedef _Float16 half4 __attribute__((ext_vector_type(4)));

#define BSHIFT 9          // 512 nodes per bucket
#define NBMAX  256        // max buckets (N <= 131072, and id must fit 17 bits)
#define CAPLOG 13         // 8192 entries per bucket (mean 6378, sigma ~80 -> +22 sigma)
#define CAP    (1 << CAPLOG)

// ---------------- binned CSR build ----------------
__launch_bounds__(256)
__global__ void k_bin(const int* __restrict__ ei, int E,
                      int* __restrict__ gcnt /* [2*NBMAX] */,
                      unsigned* __restrict__ binbuf /* [2*NBMAX*CAP] */) {
    __shared__ int lcnt[2 * NBMAX];
    const int tid = threadIdx.x;
    lcnt[tid] = 0; lcnt[NBMAX + tid] = 0;
    __syncthreads();
    const int start = blockIdx.x * 8192;
    const int end = min(start + 8192, E);
    for (int e = start + tid; e < end; e += 256) {
        int s = ei[e], d = ei[E + e];
        atomicAdd(&lcnt[d >> BSHIFT], 1);           // in-dir: bucket by dst
        atomicAdd(&lcnt[NBMAX + (s >> BSHIFT)], 1); // out-dir: bucket by src
    }
    __syncthreads();
    {   // reserve contiguous runs in each bucket; cursor = global base
        int c0 = lcnt[tid], c1 = lcnt[NBMAX + tid];
        int b0 = c0 ? atomicAdd(&gcnt[tid], c0) : 0;
        int b1 = c1 ? atomicAdd(&gcnt[NBMAX + tid], c1) : 0;
        lcnt[tid] = b0; lcnt[NBMAX + tid] = b1;
    }
    __syncthreads();
    for (int e = start + tid; e < end; e += 256) {  // ei re-read is L2-hot
        int s = ei[e], d = ei[E + e];
        int bi = d >> BSHIFT;
        int p = atomicAdd(&lcnt[bi], 1);
        if (p < CAP)
            binbuf[(bi << CAPLOG) + p] = ((unsigned)(d & 511) << 17) | (unsigned)s;
        int bo = s >> BSHIFT;
        int p2 = atomicAdd(&lcnt[NBMAX + bo], 1);
        if (p2 < CAP)
            binbuf[((NBMAX + bo) << CAPLOG) + p2] = ((unsigned)(s & 511) << 17) | (unsigned)d;
    }
}

// Pass B: per (bucket,dir) block. In-LDS scan of gcnt -> bucket base; LDS degree
// histogram -> Blelloch exclusive scan -> write rp + scatter ci via LDS cursors.
__launch_bounds__(256)
__global__ void k_binfill2(const unsigned* __restrict__ binbuf, const int* __restrict__ gcnt,
                           int n,
                           int* __restrict__ rp_in, int* __restrict__ rp_out,
                           int* __restrict__ ci_in, int* __restrict__ ci_out) {
    __shared__ int h[512];     // histogram -> exclusive scan
    __shared__ int cur[512];   // scatter cursors
    __shared__ int gb[NBMAX];  // bucket-total scan for base offset
    __shared__ int s_tot;
    const int dir = blockIdx.y, bkt = blockIdx.x, tid = threadIdx.x;
    int* rp = dir ? rp_out : rp_in;
    int* ci = dir ? ci_out : ci_in;
    h[tid] = 0; h[256 + tid] = 0;
    gb[tid] = gcnt[dir * NBMAX + tid];
    __syncthreads();
    for (int off = 1; off < NBMAX; off <<= 1) {
        int t = (tid >= off) ? gb[tid - off] : 0;
        __syncthreads();
        gb[tid] += t;
        __syncthreads();
    }
    const int base_off = bkt ? gb[bkt - 1] : 0;
    const int cnt = min(gcnt[dir * NBMAX + bkt], CAP);
    const unsigned* buf = binbuf + (((size_t)dir * NBMAX + bkt) << CAPLOG);
    for (int i = tid; i < cnt; i += 256)
        atomicAdd(&h[buf[i] >> 17], 1);
    __syncthreads();
    for (int d = 1; d < 512; d <<= 1) {
        int idx = (tid + 1) * (d << 1) - 1;
        if (idx < 512) h[idx] += h[idx - d];
        __syncthreads();
    }
    if (tid == 0) { s_tot = h[511]; h[511] = 0; }
    __syncthreads();
    for (int d = 256; d >= 1; d >>= 1) {
        int idx = (tid + 1) * (d << 1) - 1;
        if (idx < 512) { int t = h[idx - d]; h[idx - d] = h[idx]; h[idx] += t; }
        __syncthreads();
    }
    const int nodebase = bkt << BSHIFT;
    for (int i = tid; i < 512; i += 256) {
        int nd = nodebase + i;
        int v = base_off + h[i];
        cur[i] = v;
        if (nd < n) rp[nd] = v;
    }
    if (tid == 0 && ((n - 1) >> BSHIFT) == bkt)
        rp[n] = base_off + s_tot;           // final row pointer
    __syncthreads();
    for (int i = tid; i < cnt; i += 256) {  // buf re-read is L2-hot (~25KB)
        unsigned ent = buf[i];
        int slot = atomicAdd(&cur[ent >> 17], 1);
        ci[slot] = (int)(ent & 0x1FFFFu);
    }
}

// ---------------- weight prep (both layers in one launch) ----------------
__global__ void k_prep2(const float* __restrict__ W1a, const float* __restrict__ W2a,
                        const float* __restrict__ Wra,
                        __bf16* __restrict__ WcTha, __bf16* __restrict__ WcTla,
                        __bf16* __restrict__ WrTha, __bf16* __restrict__ WrTla,
                        const float* __restrict__ W1b, const float* __restrict__ W2b,
                        const float* __restrict__ Wrb,
                        __bf16* __restrict__ WcThb, __bf16* __restrict__ WcTlb,
                        __bf16* __restrict__ WrThb, __bf16* __restrict__ WrTlb) {
    const float *W1, *W2, *Wr;
    __bf16 *Wch, *Wcl, *Wrh, *Wrl;
    if (blockIdx.y == 0) { W1 = W1a; W2 = W2a; Wr = Wra; Wch = WcTha; Wcl = WcTla; Wrh = WrTha; Wrl = WrTla; }
    else                 { W1 = W1b; W2 = W2b; Wr = Wrb; Wch = WcThb; Wcl = WcTlb; Wrh = WrThb; Wrl = WrTlb; }
    int i = blockIdx.x * 256 + threadIdx.x;  // 12288 total
    if (i < 8192) {
        int nn = i >> 7, k = i & 127;
        float w = (k < 64) ? W1[k * 64 + nn] : W2[(k - 64) * 64 + nn];
        __bf16 h = (__bf16)w;
        Wch[i] = h;
        Wcl[i] = (__bf16)(w - (float)h);
    } else if (i < 12288) {
        int j = i - 8192;
        int nn = j >> 6, k = j & 63;
        float w = Wr[k * 64 + nn];
        __bf16 h = (__bf16)w;
        Wrh[j] = h;
        Wrl[j] = (__bf16)(w - (float)h);
    }
}

// ---------------- fp32 -> fp16 feature table (layer-1 input) ----------------
__global__ void k_tohalf(const float* __restrict__ X, _Float16* __restrict__ F, int n64) {
    int i = (blockIdx.x * 256 + threadIdx.x) * 4;
    if (i >= n64) return;
    float4 v = *(const float4*)(X + i);
    half4 h = { (_Float16)v.x, (_Float16)v.y, (_Float16)v.z, (_Float16)v.w };
    *(half4*)(F + i) = h;
}

// ---------------- gather: fp16 rows (128B), r7 loop shape ----------------
// lane = 16*sub + q; q covers 4 cols (8B), sub picks row-within-group; 8 rows
// in flight per dir. Means accumulate fp32; A written split-bf16.
__launch_bounds__(256, 8)
__global__ void k_gather(const _Float16* __restrict__ F,
                         const int* __restrict__ rp_in, const int* __restrict__ ci_in,
                         const int* __restrict__ rp_out, const int* __restrict__ ci_out,
                         __bf16* __restrict__ Ah, __bf16* __restrict__ Al, int n) {
    const int lane = threadIdx.x & 63;
    const int wid  = threadIdx.x >> 6;
    const int v = blockIdx.x * 4 + wid;
    if (v >= n) return;
    const int q = lane & 15, sub = lane >> 4;
    const _Float16* __restrict__ fq = F + q * 4;

    #pragma unroll
    for (int dir = 0; dir < 2; ++dir) {
        const int* rp = dir ? rp_out : rp_in;
        const int* ci = dir ? ci_out : ci_in;
        int s = rp[v], e = rp[v + 1];
        float ax = 0.f, ay = 0.f, az = 0.f, aw = 0.f;
        int t = s;
        for (; t + 8 <= e; t += 8) {  // 8 rows per iter
            int u0 = ci[t + sub];
            int u1 = ci[t + 4 + sub];
            half4 f0 = *(const half4*)(fq + (size_t)u0 * 64);
            half4 f1 = *(const half4*)(fq + (size_t)u1 * 64);
            ax += (float)f0[0] + (float)f1[0];
            ay += (float)f0[1] + (float)f1[1];
            az += (float)f0[2] + (float)f1[2];
            aw += (float)f0[3] + (float)f1[3];
        }
        for (; t < e; t += 4) {  // tail, predicated per sub-group
            int r = t + sub;
            if (r < e) {
                half4 f = *(const half4*)(fq + (size_t)ci[r] * 64);
                ax += (float)f[0]; ay += (float)f[1];
                az += (float)f[2]; aw += (float)f[3];
            }
        }
        ax += __shfl_xor(ax, 16, 64); ax += __shfl_xor(ax, 32, 64);
        ay += __shfl_xor(ay, 16, 64); ay += __shfl_xor(ay, 32, 64);
        az += __shfl_xor(az, 16, 64); az += __shfl_xor(az, 32, 64);
        aw += __shfl_xor(aw, 16, 64); aw += __shfl_xor(aw, 32, 64);
        float inv = 1.0f / (float)max(e - s, 1);
        ax *= inv; ay *= inv; az *= inv; aw *= inv;

        if (sub == 0) {  // 16 lanes write the 64-col block as split bf16
            union { __bf16 h[4]; uint2 u2; } ph, pl;
            float m[4] = {ax, ay, az, aw};
            #pragma unroll
            for (int c = 0; c < 4; ++c) {
                __bf16 h = (__bf16)m[c];
                ph.h[c] = h;
                pl.h[c] = (__bf16)(m[c] - (float)h);
            }
            size_t off = (size_t)v * 128 + dir * 64 + q * 4;
            *(uint2*)(Ah + off) = ph.u2;
            *(uint2*)(Al + off) = pl.u2;
        }
    }
}

// ---------------- MFMA GEMM: out = relu(A@Wcat + Hin@Wr + br) ----------------
// mfma_f32_16x16x32_bf16; identical k-packing for A and B cancels internal
// k-order. C/D: col = lane&15, row = (lane>>4)*4 + reg  [verified m89]
// Optionally also stores the output as fp16 (feature table for next layer's gather).
__global__ void k_gemm(const __bf16* __restrict__ Ah, const __bf16* __restrict__ Al,
                       const float* __restrict__ Hin,
                       const __bf16* __restrict__ WcT_h, const __bf16* __restrict__ WcT_l,
                       const __bf16* __restrict__ WrT_h, const __bf16* __restrict__ WrT_l,
                       const float* __restrict__ br, float* __restrict__ Hout,
                       _Float16* __restrict__ Fout, int n) {
    const int lane = threadIdx.x & 63;
    const int wid  = threadIdx.x >> 6;
    const int q = lane & 15, sub = lane >> 4;
    const int rowbase = blockIdx.x * 64 + wid * 16;
    const int arow = min(rowbase + q, n - 1);

    f32x4 acc[4];
    #pragma unroll
    for (int nf = 0; nf < 4; ++nf) acc[nf] = (f32x4){0.f, 0.f, 0.f, 0.f};

    // A @ Wcat  (K = 128)
    #pragma unroll
    for (int ks = 0; ks < 4; ++ks) {
        const size_t ao = (size_t)arow * 128 + ks * 32 + sub * 8;
        bf16x8 a_h = *(const bf16x8*)(Ah + ao);
        bf16x8 a_l = *(const bf16x8*)(Al + ao);
        #pragma unroll
        for (int nf = 0; nf < 4; ++nf) {
            const size_t bo = (size_t)(nf * 16 + q) * 128 + ks * 32 + sub * 8;
            bf16x8 b_h = *(const bf16x8*)(WcT_h + bo);
            bf16x8 b_l = *(const bf16x8*)(WcT_l + bo);
            acc[nf] = __builtin_amdgcn_mfma_f32_16x16x32_bf16(a_h, b_h, acc[nf], 0, 0, 0);
            acc[nf] = __builtin_amdgcn_mfma_f32_16x16x32_bf16(a_h, b_l, acc[nf], 0, 0, 0);
            acc[nf] = __builtin_amdgcn_mfma_f32_16x16x32_bf16(a_l, b_h, acc[nf], 0, 0, 0);
        }
    }
    // Hin @ Wr  (K = 64), fp32 -> hi/lo split in-register
    #pragma unroll
    for (int ks = 0; ks < 2; ++ks) {
        const float* hp = Hin + (size_t)arow * 64 + ks * 32 + sub * 8;
        float4 h0 = *(const float4*)hp;
        float4 h1 = *(const float4*)(hp + 4);
        float hf[8] = {h0.x, h0.y, h0.z, h0.w, h1.x, h1.y, h1.z, h1.w};
        bf16x8 a_h, a_l;
        #pragma unroll
        for (int c = 0; c < 8; ++c) {
            __bf16 h = (__bf16)hf[c];
            a_h[c] = h;
            a_l[c] = (__bf16)(hf[c] - (float)h);
        }
        #pragma unroll
        for (int nf = 0; nf < 4; ++nf) {
            const size_t bo = (size_t)(nf * 16 + q) * 64 + ks * 32 + sub * 8;
            bf16x8 b_h = *(const bf16x8*)(WrT_h + bo);
            bf16x8 b_l = *(const bf16x8*)(WrT_l + bo);
            acc[nf] = __builtin_amdgcn_mfma_f32_16x16x32_bf16(a_h, b_h, acc[nf], 0, 0, 0);
            acc[nf] = __builtin_amdgcn_mfma_f32_16x16x32_bf16(a_h, b_l, acc[nf], 0, 0, 0);
            acc[nf] = __builtin_amdgcn_mfma_f32_16x16x32_bf16(a_l, b_h, acc[nf], 0, 0, 0);
        }
    }
    #pragma unroll
    for (int nf = 0; nf < 4; ++nf) {
        int col = nf * 16 + q;
        float b = br[col];
        #pragma unroll
        for (int reg = 0; reg < 4; ++reg) {
            int row = rowbase + sub * 4 + reg;
            if (row < n) {
                float val = fmaxf(acc[nf][reg] + b, 0.f);
                Hout[(size_t)row * 64 + col] = val;
                if (Fout) Fout[(size_t)row * 64 + col] = (_Float16)val;
            }
        }
    }
}

extern "C" void kernel_launch(void* const* d_in, const int* in_sizes, int n_in,
                              void* d_out, int out_size, void* d_ws, size_t ws_size,
                              hipStream_t stream) {
    const float* x    = (const float*)d_in[0];
    const int*   ei   = (const int*)d_in[1];
    const float* W1_0 = (const float*)d_in[2];
    const float* W2_0 = (const float*)d_in[3];
    const float* Wr_0 = (const float*)d_in[4];
    const float* br_0 = (const float*)d_in[5];
    const float* W1_1 = (const float*)d_in[6];
    const float* W2_1 = (const float*)d_in[7];
    const float* Wr_1 = (const float*)d_in[8];
    const float* br_1 = (const float*)d_in[9];
    float* out = (float*)d_out;

    const int N = in_sizes[0] / 64;
    const int E = in_sizes[1] / 2;
    const int NB = (N + 511) >> BSHIFT;       // 196 buckets (<= NBMAX)

    // bump allocator over d_ws (re-poisoned every call -> rebuild everything)
    char* p = (char*)d_ws;
    auto alloc = [&](size_t bytes) { char* r = p; p += (bytes + 255) & ~255ULL; return r; };

    int* rp_in   = (int*)alloc(((size_t)N + 1) * 4);
    int* rp_out  = (int*)alloc(((size_t)N + 1) * 4);
    int* gcnt    = (int*)alloc(2 * NBMAX * 4);
    int* ci_in   = (int*)alloc((size_t)E * 4);
    int* ci_out  = (int*)alloc((size_t)E * 4);
    __bf16* Ah   = (__bf16*)alloc((size_t)N * 128 * 2);
    __bf16* Al   = (__bf16*)alloc((size_t)N * 128 * 2);
    float* H     = (float*)alloc((size_t)N * 64 * 4);
    _Float16* F  = (_Float16*)alloc((size_t)N * 64 * 2);   // fp16 gather table (x, then H)
    __bf16* WcT_h0 = (__bf16*)alloc(8192 * 2);
    __bf16* WcT_l0 = (__bf16*)alloc(8192 * 2);
    __bf16* WrT_h0 = (__bf16*)alloc(4096 * 2);
    __bf16* WrT_l0 = (__bf16*)alloc(4096 * 2);
    __bf16* WcT_h1 = (__bf16*)alloc(8192 * 2);
    __bf16* WcT_l1 = (__bf16*)alloc(8192 * 2);
    __bf16* WrT_h1 = (__bf16*)alloc(4096 * 2);
    __bf16* WrT_l1 = (__bf16*)alloc(4096 * 2);

    // binbuf (2*NBMAX*CAP*4B = 16.8MB) aliases Ah/Al: dead before first k_gather.
    unsigned* binbuf = (unsigned*)Ah;

    hipMemsetAsync(gcnt, 0, 2 * NBMAX * 4, stream);

    int bb = (E + 8191) / 8192;
    k_bin<<<bb, 256, 0, stream>>>(ei, E, gcnt, binbuf);
    k_binfill2<<<dim3(NB, 2), 256, 0, stream>>>(binbuf, gcnt, N,
                                                rp_in, rp_out, ci_in, ci_out);
    k_prep2<<<dim3(48, 2), 256, 0, stream>>>(W1_0, W2_0, Wr_0, WcT_h0, WcT_l0, WrT_h0, WrT_l0,
                                             W1_1, W2_1, Wr_1, WcT_h1, WcT_l1, WrT_h1, WrT_l1);
    k_tohalf<<<(N * 64 / 4 + 255) / 256, 256, 0, stream>>>(x, F, N * 64);

    int gb = (N + 3) / 4;           // 4 nodes per 256-thread block
    int mb = (N + 63) / 64;         // 64 rows per GEMM block

    k_gather<<<gb, 256, 0, stream>>>(F, rp_in, ci_in, rp_out, ci_out, Ah, Al, N);
    k_gemm<<<mb, 256, 0, stream>>>(Ah, Al, x, WcT_h0, WcT_l0, WrT_h0, WrT_l0, br_0, H, F, N);

    k_gather<<<gb, 256, 0, stream>>>(F, rp_in, ci_in, rp_out, ci_out, Ah, Al, N);
    k_gemm<<<mb, 256, 0, stream>>>(Ah, Al, H, WcT_h1, WcT_l1, WrT_h1, WrT_l1, br_1, out,
                                   (_Float16*)nullptr, N);
}